// Round 7
// baseline (56.469 us; speedup 1.0000x reference)
//
#include <hip/hip_runtime.h>
#include <math.h>

// (B,T,C)=(16,2048,1024), H=16, K=31, R=64, causal pad P=30.
// out[b,t,c] = sum_{j=0..30} w_rev[h(c),j] * x[b,t-j,c],  w_rev[j] = softmax(w)[30-j]
//
// Persistent double-buffered pipeline (T3/T4 minimum form):
//   512 blocks = exactly 2/CU (80 KB LDS each), each owns 8 t-tiles of 128 rows.
//   per tile: STAGE(next, buf^1) -> compute(cur) -> s_waitcnt vmcnt(16) -> s_barrier.
//   vmcnt(16): 16 = stores issued this iter (newest); waits only the 10 DMA issues
//   (older) of the NEXT tile -> HBM queue never drains to empty (round-6 failure mode).
#define TPB  256
#define KW   31
#define HALO 30
#define TT   16                // outputs per thread (= stores per thread per tile)
#define BT   128               // t-rows per tile
#define RQ   40                // staged quads per tile (160 rows x 256 B = 40 KB)
#define NT   8                 // tiles per block
constexpr int B_ = 16, T_ = 2048, C_ = 1024, H_ = 16;
constexpr int C2  = C_ / 2;    // float2 pairs per t-row
constexpr int PPH = 32;        // float2 pairs per head

__global__ void zerows_kernel(float* ws) { ws[threadIdx.x] = 0.f; }   // 512 B zero page

__device__ inline float rfl(float v) {   // lane-uniform float -> SGPR
    return __builtin_bit_cast(float, __builtin_amdgcn_readfirstlane(__builtin_bit_cast(int, v)));
}

__global__ __launch_bounds__(TPB) void lconv_kernel(const float* __restrict__ x,
                                                    const float* __restrict__ w,
                                                    const float* __restrict__ zp,
                                                    float* __restrict__ out) {
    __shared__ float smem[2][RQ * 256];      // 2 x 40 KB
    const int bid = blockIdx.x;
    const int h   = bid & 15;
    const int b   = (bid >> 4) & 15;
    const int yh  = bid >> 8;                // 0..1 -> tiles y = yh*8 .. yh*8+7
    const int tid  = threadIdx.x;
    const int lane = tid & 63, wid = tid >> 6;
    const int qrow = lane >> 4, chunk = lane & 15;
    const int pair = tid & 31,  sub = tid >> 5;   // compute mapping (8 subtiles x 16 rows)

    const float* xh = x + (size_t)b * T_ * C_ + h * 64;

    // ---- stage one tile into smem[buf]: rows t0b-30 .. t0b+129 (160 rows x 256 B)
    auto stage = [&](const int buf, const int kt) {
        const int t0b = (yh * NT + kt) * BT;
        #pragma unroll
        for (int q = wid; q < RQ; q += 4) {          // 10 DMA per wave
            const int t = t0b - HALO + 4 * q + qrow;
            const float* src = (t < 0) ? (zp + chunk * 4)
                                       : (xh + (size_t)min(t, T_ - 1) * C_ + chunk * 4);
            __builtin_amdgcn_global_load_lds(
                (const __attribute__((address_space(1))) uint32_t*)src,
                (__attribute__((address_space(3))) uint32_t*)(&smem[buf][q * 256]),
                16, 0, 0);
        }
    };

    // ---- prologue: DMA tile 0; softmax(w[h]) under the DMA; full drain once.
    stage(0, 0);
    float wv[KW];
    {
        float v[KW]; float m = -1e30f;
        #pragma unroll
        for (int k = 0; k < KW; ++k) { v[k] = w[h * KW + k]; m = fmaxf(m, v[k]); }
        float s = 0.f;
        #pragma unroll
        for (int k = 0; k < KW; ++k) { v[k] = __expf(v[k] - m); s += v[k]; }
        const float inv = 1.f / s;
        #pragma unroll
        for (int j = 0; j < KW; ++j) wv[j] = rfl(v[KW - 1 - j] * inv);   // reversed -> SGPR
    }
    asm volatile("s_waitcnt vmcnt(0) lgkmcnt(0)" ::: "memory");
    __builtin_amdgcn_s_barrier();
    __builtin_amdgcn_sched_barrier(0);

    // ---- steady state
    auto process = [&](const int buf, const int kt) {    // buf is compile-time at call sites
        if (kt + 1 < NT) stage(buf ^ 1, kt + 1);
        __builtin_amdgcn_sched_barrier(0);

        const int t0b = (yh * NT + kt) * BT;
        float2 acc[TT];
        #pragma unroll
        for (int i = 0; i < TT; ++i) acc[i] = make_float2(0.f, 0.f);

        const float2* sm2 = (const float2*)smem[buf];
        #pragma unroll
        for (int sr = 0; sr < TT + HALO; ++sr) {         // 46 LDS rows per thread
            const float2 v = sm2[(sub * TT + sr) * PPH + pair];
            const int ilo = (sr - HALO < 0) ? 0 : sr - HALO;
            const int ihi = (sr < TT - 1) ? sr : TT - 1;
            #pragma unroll
            for (int i = ilo; i <= ihi; ++i) {           // j = i + HALO - sr, static
                const float wj = wv[i + HALO - sr];
                acc[i].x = fmaf(wj, v.x, acc[i].x);
                acc[i].y = fmaf(wj, v.y, acc[i].y);
            }
        }

        float2* po = (float2*)out + ((size_t)b * T_ + t0b + sub * TT) * C2 + h * PPH + pair;
        #pragma unroll
        for (int i = 0; i < TT; ++i) po[(size_t)i * C2] = acc[i];       // 16 dwordx2 stores

        if (kt + 1 < NT) {
            // drain ONLY the next tile's 10 DMA (older than the 16 stores above)
            asm volatile("s_waitcnt vmcnt(16) lgkmcnt(0)" ::: "memory");
            __builtin_amdgcn_s_barrier();
            __builtin_amdgcn_sched_barrier(0);
        }
    };

    #pragma unroll 1
    for (int kp = 0; kp < NT / 2; ++kp) {
        process(0, 2 * kp);
        process(1, 2 * kp + 1);
    }
}

extern "C" void kernel_launch(void* const* d_in, const int* in_sizes, int n_in,
                              void* d_out, int out_size, void* d_ws, size_t ws_size,
                              hipStream_t stream) {
    const float* x = (const float*)d_in[0];
    const float* w = (const float*)d_in[1];
    float* out = (float*)d_out;
    float* zp  = (float*)d_ws;                 // 512 B zero page for t<0 halo

    hipLaunchKernelGGL(zerows_kernel, dim3(1), dim3(128), 0, stream, zp);

    dim3 grid(512);                            // 16h x 16b x 2 y-halves = exactly 2/CU
    hipLaunchKernelGGL(lconv_kernel, grid, dim3(TPB), 0, stream, x, w, zp, out);
}

// Round 8
// 46.697 us; speedup vs baseline: 1.2093x; 1.2093x over previous
//
#include <hip/hip_runtime.h>
#include <math.h>

// (B,T,C)=(16,2048,1024), H=16, K=31, R=64, causal pad P=30.
// out[b,t,c] = sum_{j=0..30} w_rev[h(c),j] * x[b,t-j,c],  w_rev[j] = softmax(w)[30-j]
//
// R5 structure (best measured: 4 blocks/CU x 4 waves, one barrier) + fused
// softmax + float4 LDS reads/stores + non-temporal stores.
#define TPB  256
#define KW   31
#define HALO 30
#define TT   8                 // outputs per thread (float4-wide)
#define BT   128               // t-rows per block
#define RQ   40                // staged quads (4 rows each -> 160 rows = 40 KB)
constexpr int B_ = 16, T_ = 2048, C_ = 1024, H_ = 16;
constexpr int C4  = C_ / 4;    // float4 per t-row (256)
constexpr int QPH = 16;        // float4 per head-row (64 ch)

typedef float f32x4 __attribute__((ext_vector_type(4)));

__device__ inline float rfl(float v) {   // lane-uniform float -> SGPR
    return __builtin_bit_cast(float, __builtin_amdgcn_readfirstlane(__builtin_bit_cast(int, v)));
}

__global__ __launch_bounds__(TPB) void lconv_kernel(const float* __restrict__ x,
                                                    const float* __restrict__ w,
                                                    float* __restrict__ out) {
    __shared__ float smem[RQ * 256];         // 160 rows * 256 B = 40 KB
    const int h   = blockIdx.x;
    const int b   = blockIdx.z;
    const int t0b = blockIdx.y * BT;
    const int tid  = threadIdx.x;
    const int lane = tid & 63, wid = tid >> 6;
    const int qrow = lane >> 4, chunk = lane & 15;

    // ---- stage 160 rows (t0b-30 .. t0b+129) of this head's 256 B column.
    // t<0 lanes: DMA skipped (exec mask), rows zero-filled below instead.
    const float* xh = x + (size_t)b * T_ * C_ + h * 64;
    #pragma unroll
    for (int q = wid; q < RQ; q += 4) {      // 10 DMA per wave
        const int t = t0b - HALO + 4 * q + qrow;
        if (t >= 0) {
            const float* src = xh + (size_t)((t < T_ - 1) ? t : T_ - 1) * C_ + chunk * 4;
            __builtin_amdgcn_global_load_lds(
                (const __attribute__((address_space(1))) uint32_t*)src,
                (__attribute__((address_space(3))) uint32_t*)(smem + q * 256),
                16, 0, 0);
        }
    }

    // ---- softmax(w[h]) under the DMA (block-uniform -> s_load + scalar-ish VALU)
    float wv[KW];
    {
        float v[KW]; float m = -1e30f;
        #pragma unroll
        for (int k = 0; k < KW; ++k) { v[k] = w[h * KW + k]; m = fmaxf(m, v[k]); }
        float s = 0.f;
        #pragma unroll
        for (int k = 0; k < KW; ++k) { v[k] = __expf(v[k] - m); s += v[k]; }
        const float inv = 1.f / s;
        #pragma unroll
        for (int j = 0; j < KW; ++j) wv[j] = rfl(v[KW - 1 - j] * inv);  // reversed -> SGPR
    }

    // zero-fill the skipped halo rows (disjoint from DMA destinations)
    if (blockIdx.y == 0) {
        for (int k = tid; k < HALO * 64; k += TPB) smem[k] = 0.f;
    }
    __syncthreads();    // compiler emits vmcnt(0)+lgkmcnt(0) drain before s_barrier

    // ---- compute: thread = (quad 0..15, sub 0..15), TT=8 rows, float4 acc
    const int quad = tid & 15;
    const int sub  = tid >> 4;

    f32x4 acc[TT];
    #pragma unroll
    for (int i = 0; i < TT; ++i) acc[i] = (f32x4)0.f;

    const f32x4* sm4 = (const f32x4*)smem;
    #pragma unroll
    for (int sr = 0; sr < TT + HALO; ++sr) {           // 38 b128 reads per thread
        const f32x4 v = sm4[(sub * TT + sr) * QPH + quad];
        const int ilo = (sr - HALO < 0) ? 0 : sr - HALO;
        const int ihi = (sr < TT - 1) ? sr : TT - 1;
        #pragma unroll
        for (int i = ilo; i <= ihi; ++i) {             // j = i + HALO - sr, static
            acc[i] += wv[i + HALO - sr] * v;
        }
    }

    // ---- non-temporal float4 stores (output is write-once, keep x in L3)
    f32x4* po = (f32x4*)out + ((size_t)b * T_ + t0b + sub * TT) * C4 + h * QPH + quad;
    #pragma unroll
    for (int i = 0; i < TT; ++i)
        __builtin_nontemporal_store(acc[i], po + (size_t)i * C4);
}

extern "C" void kernel_launch(void* const* d_in, const int* in_sizes, int n_in,
                              void* d_out, int out_size, void* d_ws, size_t ws_size,
                              hipStream_t stream) {
    const float* x = (const float*)d_in[0];
    const float* w = (const float*)d_in[1];
    float* out = (float*)d_out;

    dim3 grid(H_, T_ / BT, B_);   // (16, 16, 16) = 4096 blocks
    hipLaunchKernelGGL(lconv_kernel, grid, dim3(TPB), 0, stream, x, w, out);
}

// Round 9
// 46.646 us; speedup vs baseline: 1.2106x; 1.0011x over previous
//
#include <hip/hip_runtime.h>
#include <math.h>

// (B,T,C)=(16,2048,1024), H=16, K=31, R=64, causal pad P=30.
// out[b,t,c] = sum_{j=0..30} w_rev[h(c),j] * x[b,t-j,c],  w_rev[j] = softmax(w)[30-j]
//
// Wave-autonomous design: block = ONE wave (TPB=64). Each wave stages its own
// 64-row x 256 B window (16 KB private LDS) via 16 async global_load_lds,
// computes softmax(w[h]) under the DMA, waits ONLY its own vmcnt (per-wave
// counter), and reads only LDS it wrote -> zero barriers, no cross-wave
// phase lock. 10 blocks/CU (LDS-capped) = 10 independent pipelines per CU,
// scheduler-staggered -> HBM queue never globally drains (rounds 5-8 all had
// block-wide burst/drain/compute phase locking).
#define TPB   64
#define KW    31
#define HALO  30
#define TT    8                 // output rows per thread (float4-wide)
#define WROWS 32                // output rows per wave/block
#define SROWS 64                // staged rows per wave (t0-32 .. t0+31)
constexpr int B_ = 16, T_ = 2048, C_ = 1024, H_ = 16;
constexpr int C4 = C_ / 4;      // float4 per t-row (256)

typedef float f32x4 __attribute__((ext_vector_type(4)));

__device__ inline float rfl(float v) {   // lane-uniform float -> SGPR
    return __builtin_bit_cast(float, __builtin_amdgcn_readfirstlane(__builtin_bit_cast(int, v)));
}

__global__ __launch_bounds__(TPB) void lconv_kernel(const float* __restrict__ x,
                                                    const float* __restrict__ w,
                                                    float* __restrict__ out) {
    __shared__ float smem[SROWS * 64];       // 16 KB, private to this single-wave block
    const int h    = blockIdx.x;             // head
    const int y    = blockIdx.y;             // t-tile (32 rows)
    const int b    = blockIdx.z;
    const int t0   = y * WROWS;
    const int lane = threadIdx.x;
    const int qrow = lane >> 4, chunk = lane & 15;   // staging map: quad=4 rows x 256 B
    const int quad = lane & 15, sl = lane >> 2 >> 2; // compute map: 16 quads x 4 subgroups

    // ---- stage rows t0-32 .. t0+31 of this head's 256 B column (16 DMA issues)
    const float* xh = x + (size_t)b * T_ * C_ + h * 64;
    #pragma unroll
    for (int q = 0; q < 16; ++q) {
        const int tq = t0 - 32 + 4 * q;      // wave-uniform guard (qrow in 0..3)
        if (tq >= 0) {
            const float* src = xh + (size_t)(tq + qrow) * C_ + chunk * 4;
            __builtin_amdgcn_global_load_lds(
                (const __attribute__((address_space(1))) uint32_t*)src,
                (__attribute__((address_space(3))) uint32_t*)(smem + q * 256),
                16, 0, 0);
        }
    }

    // ---- softmax(w[h]) under the DMA (block-uniform -> s_load + uniform VALU)
    float wv[KW];
    {
        float v[KW]; float m = -1e30f;
        #pragma unroll
        for (int k = 0; k < KW; ++k) { v[k] = w[h * KW + k]; m = fmaxf(m, v[k]); }
        float s = 0.f;
        #pragma unroll
        for (int k = 0; k < KW; ++k) { v[k] = __expf(v[k] - m); s += v[k]; }
        const float inv = 1.f / s;
        #pragma unroll
        for (int j = 0; j < KW; ++j) wv[j] = rfl(v[KW - 1 - j] * inv);  // reversed -> SGPR
    }

    // ---- zero-fill the DMA-skipped halo rows (y==0: rows 0..31; disjoint addrs)
    if (y == 0) {
        f32x4* s4 = (f32x4*)smem;
        #pragma unroll
        for (int k = 0; k < 8; ++k) s4[k * 64 + lane] = (f32x4)0.f;
    }

    // per-wave wait: only OUR 16 DMAs + our ds_writes; no barrier
    asm volatile("s_waitcnt vmcnt(0) lgkmcnt(0)" ::: "memory");
    __builtin_amdgcn_sched_barrier(0);

    // ---- compute: lane = (sl 0..3, quad 0..15); out rows t0+8*sl .. +7
    f32x4 acc[TT];
    #pragma unroll
    for (int i = 0; i < TT; ++i) acc[i] = (f32x4)0.f;

    const f32x4* sm4 = (const f32x4*)smem;
    #pragma unroll
    for (int sr = 0; sr < TT + HALO; ++sr) {           // LDS rows 8*sl+2 .. 8*sl+39
        const f32x4 v = sm4[(8 * sl + 2 + sr) * 16 + quad];
        const int ilo = (sr - HALO < 0) ? 0 : sr - HALO;
        const int ihi = (sr < TT - 1) ? sr : TT - 1;
        #pragma unroll
        for (int i = ilo; i <= ihi; ++i) {             // weight idx i+30-sr, static
            acc[i] += wv[i + HALO - sr] * v;
        }
    }

    // ---- non-temporal float4 stores (write-once output)
    f32x4* po = (f32x4*)out + ((size_t)b * T_ + t0 + 8 * sl) * C4 + h * 16 + quad;
    #pragma unroll
    for (int i = 0; i < TT; ++i)
        __builtin_nontemporal_store(acc[i], po + (size_t)i * C4);
}

extern "C" void kernel_launch(void* const* d_in, const int* in_sizes, int n_in,
                              void* d_out, int out_size, void* d_ws, size_t ws_size,
                              hipStream_t stream) {
    const float* x = (const float*)d_in[0];
    const float* w = (const float*)d_in[1];
    float* out = (float*)d_out;

    dim3 grid(H_, T_ / WROWS, B_);   // (16, 64, 16) = 16384 single-wave blocks
    hipLaunchKernelGGL(lconv_kernel, grid, dim3(TPB), 0, stream, x, w, out);
}